// Round 15
// baseline (1271.690 us; speedup 1.0000x reference)
//
#include <hip/hip_runtime.h>
#include <hip/hip_bf16.h>
#include <stdint.h>

typedef __attribute__((ext_vector_type(8))) short bf16x8;
typedef __attribute__((ext_vector_type(4))) float f32x4;
typedef unsigned short ushort_t;
typedef unsigned int uint_t;

__device__ __forceinline__ unsigned short f2bf(float f) {
  unsigned u = __float_as_uint(f);
  u += 0x7fffu + ((u >> 16) & 1u);
  return (unsigned short)(u >> 16);
}
__device__ __forceinline__ float bf2f(unsigned u16) {
  return __uint_as_float(u16 << 16);
}
__device__ __forceinline__ void fma8(float* a, uint4 u, float w) {
  a[0] += w * bf2f(u.x & 0xffffu); a[1] += w * bf2f(u.x >> 16);
  a[2] += w * bf2f(u.y & 0xffffu); a[3] += w * bf2f(u.y >> 16);
  a[4] += w * bf2f(u.z & 0xffffu); a[5] += w * bf2f(u.z >> 16);
  a[6] += w * bf2f(u.w & 0xffffu); a[7] += w * bf2f(u.w >> 16);
}
__device__ __forceinline__ uint4 pack8u(const float* a) {
  uint4 p;
  p.x = (uint_t)f2bf(a[0]) | ((uint_t)f2bf(a[1]) << 16);
  p.y = (uint_t)f2bf(a[2]) | ((uint_t)f2bf(a[3]) << 16);
  p.z = (uint_t)f2bf(a[4]) | ((uint_t)f2bf(a[5]) << 16);
  p.w = (uint_t)f2bf(a[6]) | ((uint_t)f2bf(a[7]) << 16);
  return p;
}

__global__ void k_zero(int* __restrict__ p, int n) {
  int i = blockIdx.x * blockDim.x + threadIdx.x;
  if (i < n) p[i] = 0;
}

// ---- weights -> bf16, swizzled [l][nt(4)][kt(16)][kg(4)][col(128)][j(8)]
// maps to W[l][k = kt*32+kg*8+j][n = nt*128+col]
__global__ void k_prep_w(const float* __restrict__ W, ushort_t* __restrict__ Wt, int total) {
  int idx = blockIdx.x * blockDim.x + threadIdx.x;
  if (idx >= total) return;
  int j   = idx & 7;
  int col = (idx >> 3) & 127;
  int kg  = (idx >> 10) & 3;
  int kt  = (idx >> 12) & 15;
  int nt  = (idx >> 16) & 3;
  int l   = idx >> 18;
  int k = kt * 32 + kg * 8 + j;
  int n = nt * 128 + col;
  Wt[idx] = f2bf(W[((size_t)(l * 512 + k)) * 512 + n]);
}

// ---- h = log1p(x) @ expW + expb   (wave per node, grid-stride, 16B stores)
__global__ __launch_bounds__(256) void k_expand(const float* __restrict__ x,
                                                const float* __restrict__ eW,
                                                const float* __restrict__ eb,
                                                ushort_t* __restrict__ h, int N) {
  const int wid = (blockIdx.x * 256 + threadIdx.x) >> 6;
  const int nw = (gridDim.x * 256) >> 6;
  const int l = threadIdx.x & 63;

  float wf[11][8];
  float bias[8];
#pragma unroll
  for (int f = 0; f < 11; ++f) {
    float4 a = *(const float4*)&eW[f * 512 + l * 8];
    float4 b = *(const float4*)&eW[f * 512 + l * 8 + 4];
    wf[f][0] = a.x; wf[f][1] = a.y; wf[f][2] = a.z; wf[f][3] = a.w;
    wf[f][4] = b.x; wf[f][5] = b.y; wf[f][6] = b.z; wf[f][7] = b.w;
  }
  {
    float4 a = *(const float4*)&eb[l * 8];
    float4 b = *(const float4*)&eb[l * 8 + 4];
    bias[0] = a.x; bias[1] = a.y; bias[2] = a.z; bias[3] = a.w;
    bias[4] = b.x; bias[5] = b.y; bias[6] = b.z; bias[7] = b.w;
  }

  for (int n = wid; n < N; n += nw) {
    float xv = (l < 11) ? x[(size_t)n * 11 + l] : 0.f;
    float lx = log1pf(xv);
    float acc[8];
#pragma unroll
    for (int j = 0; j < 8; ++j) acc[j] = bias[j];
#pragma unroll
    for (int f = 0; f < 11; ++f) {
      float c = __shfl(lx, f, 64);
#pragma unroll
      for (int j = 0; j < 8; ++j) acc[j] += c * wf[f][j];
    }
    *(uint4*)(h + (size_t)n * 512 + l * 8) = pack8u(acc);
  }
}

__global__ void k_deg(const int* __restrict__ dst, int* __restrict__ deg, int E) {
  int e = blockIdx.x * blockDim.x + threadIdx.x;
  if (e < E) atomicAdd(&deg[dst[e]], 1);
}

__global__ void k_dinv(const int* __restrict__ deg, float* __restrict__ dinv,
                       float* __restrict__ selfn, int N) {
  int n = blockIdx.x * blockDim.x + threadIdx.x;
  if (n >= N) return;
  float d = (float)deg[n] + 2.0f;
  dinv[n] = rsqrtf(d);
  selfn[n] = 2.0f / d;
}

// ---- 2-level exclusive scan of deg -> off (CSR offsets)
__global__ void k_scan_a(const int* __restrict__ deg, int* __restrict__ off,
                         int* __restrict__ bsum, int N) {
  __shared__ int sd[256];
  int t = threadIdx.x;
  int i0 = blockIdx.x * 1024 + t * 4;
  int d[4];
#pragma unroll
  for (int j = 0; j < 4; ++j) d[j] = (i0 + j < N) ? deg[i0 + j] : 0;
  int ts = d[0] + d[1] + d[2] + d[3];
  sd[t] = ts;
  __syncthreads();
  for (int o = 1; o < 256; o <<= 1) {
    int v = (t >= o) ? sd[t - o] : 0;
    __syncthreads();
    sd[t] += v;
    __syncthreads();
  }
  int incl = sd[t];
  int run = incl - ts;
#pragma unroll
  for (int j = 0; j < 4; ++j) {
    if (i0 + j < N) off[i0 + j] = run;
    run += d[j];
  }
  if (t == 255) bsum[blockIdx.x] = incl;
}

__global__ void k_scan_b(const int* __restrict__ bsum, int* __restrict__ bpre, int nb,
                         int* __restrict__ off, int N, int E) {
  __shared__ int sd[256];
  int t = threadIdx.x;
  int v = (t < nb) ? bsum[t] : 0;
  sd[t] = v;
  __syncthreads();
  for (int o = 1; o < 256; o <<= 1) {
    int u = (t >= o) ? sd[t - o] : 0;
    __syncthreads();
    sd[t] += u;
    __syncthreads();
  }
  if (t < nb) bpre[t] = sd[t] - v;
  if (t == 0) off[N] = E;
}

__global__ void k_scan_c(int* __restrict__ off, const int* __restrict__ bpre, int N) {
  int i = blockIdx.x * blockDim.x + threadIdx.x;
  if (i < N) off[i] += bpre[i >> 10];
}

__global__ void k_fill(const int* __restrict__ src, const int* __restrict__ dst,
                       const int* __restrict__ off, int* __restrict__ cur,
                       int* __restrict__ ssrc, int E) {
  int e = blockIdx.x * blockDim.x + threadIdx.x;
  if (e >= E) return;
  int t = dst[e];
  int p = atomicAdd(&cur[t], 1);
  ssrc[off[t] + p] = src[e];
}

// ---- s = A_hat * h  (two nodes per wave, distance-1 pipelined chains;
//      node ranges aligned to the GEMM's XCD-chunk map)
__global__ __launch_bounds__(256) void k_agg2(const ushort_t* __restrict__ h,
                                              ushort_t* __restrict__ s,
                                              const int* __restrict__ off,
                                              const int* __restrict__ ssrc,
                                              const float* __restrict__ dinv,
                                              const float* __restrict__ selfn,
                                              int N, int q, int r) {
  const int b = blockIdx.x;
  const int x = b & 7;
  const int ib = b >> 3;
  const int bpx = gridDim.x >> 3;
  const int wv = threadIdx.x >> 6;
  const int l = threadIdx.x & 63;

  auto swz_lo = [&](int xx) { return xx < r ? xx * (q + 1) : r * (q + 1) + (xx - r) * q; };
  const int node_lo = swz_lo(x) * 32;
  const int node_hi = min(N, swz_lo(x + 1) * 32);
  const int stride = bpx * 4 * 2;

  for (int n0 = node_lo + (ib * 4 + wv) * 2; n0 < node_hi; n0 += stride) {
    const int n1 = n0 + 1;
    const bool v1 = n1 < node_hi;
    int i0 = off[n0], e0 = off[n0 + 1];
    int i1 = v1 ? e0 : 0, e1 = v1 ? off[n1 + 1] : 0;
    float dn0 = dinv[n0], dn1 = v1 ? dinv[n1] : 0.f;
    float a0[8], a1[8];
    {
      uint4 u = *(const uint4*)(h + (size_t)n0 * 512 + l * 8);
      float sn = selfn[n0];
      a0[0] = sn * bf2f(u.x & 0xffffu); a0[1] = sn * bf2f(u.x >> 16);
      a0[2] = sn * bf2f(u.y & 0xffffu); a0[3] = sn * bf2f(u.y >> 16);
      a0[4] = sn * bf2f(u.z & 0xffffu); a0[5] = sn * bf2f(u.z >> 16);
      a0[6] = sn * bf2f(u.w & 0xffffu); a0[7] = sn * bf2f(u.w >> 16);
    }
#pragma unroll
    for (int j = 0; j < 8; ++j) a1[j] = 0.f;
    if (v1) {
      uint4 u = *(const uint4*)(h + (size_t)n1 * 512 + l * 8);
      fma8(a1, u, selfn[n1]);
    }

    const int cj = min(e0 - i0, e1 - i1);
    if (cj > 0) {
      int m0 = ssrc[i0], m1 = ssrc[i1];
      float w0 = dn0 * dinv[m0], w1 = dn1 * dinv[m1];
      uint4 u0 = *(const uint4*)(h + (size_t)m0 * 512 + l * 8);
      uint4 u1 = *(const uint4*)(h + (size_t)m1 * 512 + l * 8);
      for (int k = 1; k < cj; ++k) {
        int m0n = ssrc[i0 + k], m1n = ssrc[i1 + k];
        float w0n = dn0 * dinv[m0n], w1n = dn1 * dinv[m1n];
        uint4 u0n = *(const uint4*)(h + (size_t)m0n * 512 + l * 8);
        uint4 u1n = *(const uint4*)(h + (size_t)m1n * 512 + l * 8);
        fma8(a0, u0, w0);
        fma8(a1, u1, w1);
        u0 = u0n; u1 = u1n; w0 = w0n; w1 = w1n;
      }
      fma8(a0, u0, w0);
      fma8(a1, u1, w1);
      i0 += cj; i1 += cj;
    }
    if (i0 < e0) {
      int m = ssrc[i0];
      float w = dn0 * dinv[m];
      uint4 u = *(const uint4*)(h + (size_t)m * 512 + l * 8);
      for (++i0; i0 < e0; ++i0) {
        int mn = ssrc[i0];
        float wn = dn0 * dinv[mn];
        uint4 un = *(const uint4*)(h + (size_t)mn * 512 + l * 8);
        fma8(a0, u, w);
        u = un; w = wn;
      }
      fma8(a0, u, w);
    }
    if (i1 < e1) {
      int m = ssrc[i1];
      float w = dn1 * dinv[m];
      uint4 u = *(const uint4*)(h + (size_t)m * 512 + l * 8);
      for (++i1; i1 < e1; ++i1) {
        int mn = ssrc[i1];
        float wn = dn1 * dinv[mn];
        uint4 un = *(const uint4*)(h + (size_t)mn * 512 + l * 8);
        fma8(a1, u, w);
        u = un; w = wn;
      }
      fma8(a1, u, w);
    }

    *(uint4*)(s + (size_t)n0 * 512 + l * 8) = pack8u(a0);
    if (v1) *(uint4*)(s + (size_t)n1 * 512 + l * 8) = pack8u(a1);
  }
}

// ---- h += relu(s @ W[l] + b)  128x128 tile, 256 thr.
//      Main loop: ZERO LDS, ZERO barriers — direct global->register operands,
//      register double-buffer (named bufs, compile-time indices).
//      XCD-chunked swizzle; LDS (16KB) used only for the coalesced epilogue.
__global__ __launch_bounds__(256) void k_gemm(const ushort_t* __restrict__ s,
                                              const ushort_t* __restrict__ Wt,
                                              const float* __restrict__ gbl,
                                              ushort_t* __restrict__ h, int N) {
  __shared__ alignas(16) float cst[32 * 128];  // 16KB epilogue staging
  const int tid = threadIdx.x;

  // bijective XCD-chunk swizzle (m204)
  const int nwg = gridDim.x * gridDim.y;
  const int orig = blockIdx.y * gridDim.x + blockIdx.x;
  const int q = nwg >> 3, r = nwg & 7;
  const int xcd = orig & 7, pos = orig >> 3;
  const int swz = (xcd < r ? xcd * (q + 1) : r * (q + 1) + (xcd - r) * q) + pos;
  const int nt = swz & 3;
  const int m0 = (swz >> 2) * 128;

  const int wv = tid >> 6, ln = tid & 63;
  const int wrow = wv >> 1, wcol = wv & 1;
  const int l15 = ln & 15, l4 = ln >> 4;

  f32x4 acc[4][4];
#pragma unroll
  for (int i = 0; i < 4; ++i)
#pragma unroll
    for (int j = 0; j < 4; ++j) acc[i][j] = (f32x4){0.f, 0.f, 0.f, 0.f};

  // per-lane operand pointers (16B fragments)
  const ushort_t* pa[4];
#pragma unroll
  for (int i = 0; i < 4; ++i) {
    int row = min(m0 + wrow * 64 + i * 16 + l15, N - 1);
    pa[i] = s + (size_t)row * 512 + l4 * 8;
  }
  const ushort_t* pb[4];
#pragma unroll
  for (int j = 0; j < 4; ++j)
    pb[j] = Wt + ((size_t)nt << 16) + (l4 * 128 + wcol * 64 + j * 16 + l15) * 8;

  bf16x8 A0[4], A1[4], B0[4], B1[4];
#pragma unroll
  for (int i = 0; i < 4; ++i) A0[i] = *(const bf16x8*)(pa[i]);
#pragma unroll
  for (int j = 0; j < 4; ++j) B0[j] = *(const bf16x8*)(pb[j]);

#pragma unroll
  for (int kt = 0; kt < 16; kt += 2) {
    // prefetch kt+1 into buf1
    if (kt + 1 < 16) {
#pragma unroll
      for (int i = 0; i < 4; ++i) A1[i] = *(const bf16x8*)(pa[i] + (kt + 1) * 32);
#pragma unroll
      for (int j = 0; j < 4; ++j) B1[j] = *(const bf16x8*)(pb[j] + (kt + 1) * 4096);
    }
    __builtin_amdgcn_s_setprio(1);
#pragma unroll
    for (int i = 0; i < 4; ++i)
#pragma unroll
      for (int j = 0; j < 4; ++j)
        acc[i][j] = __builtin_amdgcn_mfma_f32_16x16x32_bf16(A0[i], B0[j], acc[i][j], 0, 0, 0);
    __builtin_amdgcn_s_setprio(0);
    // prefetch kt+2 into buf0
    if (kt + 2 < 16) {
#pragma unroll
      for (int i = 0; i < 4; ++i) A0[i] = *(const bf16x8*)(pa[i] + (kt + 2) * 32);
#pragma unroll
      for (int j = 0; j < 4; ++j) B0[j] = *(const bf16x8*)(pb[j] + (kt + 2) * 4096);
    }
    if (kt + 1 < 16) {
      __builtin_amdgcn_s_setprio(1);
#pragma unroll
      for (int i = 0; i < 4; ++i)
#pragma unroll
        for (int j = 0; j < 4; ++j)
          acc[i][j] = __builtin_amdgcn_mfma_f32_16x16x32_bf16(A1[i], B1[j], acc[i][j], 0, 0, 0);
      __builtin_amdgcn_s_setprio(0);
    }
  }

  // epilogue: 4 passes of 32 rows x 128 cols f32 through cst, coalesced RMW
#pragma unroll
  for (int p = 0; p < 4; ++p) {
    const int wrow_sel = p >> 1, ipair = (p & 1) * 2;
    if (wrow == wrow_sel) {
#pragma unroll
      for (int ii = 0; ii < 2; ++ii) {
        int i = ipair + ii;
#pragma unroll
        for (int v = 0; v < 4; ++v) {
          int r32 = ii * 16 + l4 * 4 + v;
#pragma unroll
          for (int j = 0; j < 4; ++j)
            cst[r32 * 128 + wcol * 64 + j * 16 + l15] = acc[i][j][v];
        }
      }
    }
    __syncthreads();
#pragma unroll
    for (int k = 0; k < 2; ++k) {
      int u = k * 256 + tid;
      int row_l = u >> 4, cb = u & 15;
      int grow = m0 + wrow_sel * 64 + ipair * 16 + row_l;
      if (grow < N) {
        float4 c0 = *(const float4*)&cst[row_l * 128 + cb * 8];
        float4 c1 = *(const float4*)&cst[row_l * 128 + cb * 8 + 4];
        float c[8] = {c0.x, c0.y, c0.z, c0.w, c1.x, c1.y, c1.z, c1.w};
        const float* gp = gbl + nt * 128 + cb * 8;
        float4 b0 = *(const float4*)gp;
        float4 b1 = *(const float4*)(gp + 4);
        float bb[8] = {b0.x, b0.y, b0.z, b0.w, b1.x, b1.y, b1.z, b1.w};
        ushort_t* hp = h + (size_t)grow * 512 + nt * 128 + cb * 8;
        uint4 hu = *(const uint4*)hp;
        float hv[8];
        hv[0] = bf2f(hu.x & 0xffffu); hv[1] = bf2f(hu.x >> 16);
        hv[2] = bf2f(hu.y & 0xffffu); hv[3] = bf2f(hu.y >> 16);
        hv[4] = bf2f(hu.z & 0xffffu); hv[5] = bf2f(hu.z >> 16);
        hv[6] = bf2f(hu.w & 0xffffu); hv[7] = bf2f(hu.w >> 16);
#pragma unroll
        for (int j = 0; j < 8; ++j) hv[j] += fmaxf(c[j] + bb[j], 0.f);
        *(uint4*)hp = pack8u(hv);
      }
    }
    __syncthreads();
  }
}

__device__ __forceinline__ int lbound(const int* a, int n, int v) {
  int lo = 0, hi = n;
  while (lo < hi) {
    int m = (lo + hi) >> 1;
    if (a[m] < v) lo = m + 1; else hi = m;
  }
  return lo;
}

// ---- global_add_pool: block per graph, 16B loads, 4-way row parallel + LDS reduce
__global__ __launch_bounds__(256) void k_pool(const ushort_t* __restrict__ h,
                                              const int* __restrict__ batch,
                                              float* __restrict__ out, int N) {
  __shared__ float red[4 * 512];
  int g = blockIdx.x;
  int t = threadIdx.x;
  int w = t >> 6, l = t & 63;
  int start = lbound(batch, N, g);
  int end = lbound(batch, N, g + 1);
  float acc[8];
#pragma unroll
  for (int j = 0; j < 8; ++j) acc[j] = 0.f;
  for (int n = start + w; n < end; n += 4) {
    uint4 u = *(const uint4*)(h + (size_t)n * 512 + l * 8);
    acc[0] += bf2f(u.x & 0xffffu); acc[1] += bf2f(u.x >> 16);
    acc[2] += bf2f(u.y & 0xffffu); acc[3] += bf2f(u.y >> 16);
    acc[4] += bf2f(u.z & 0xffffu); acc[5] += bf2f(u.z >> 16);
    acc[6] += bf2f(u.w & 0xffffu); acc[7] += bf2f(u.w >> 16);
  }
#pragma unroll
  for (int j = 0; j < 8; ++j) red[w * 512 + l * 8 + j] = acc[j];
  __syncthreads();
  if (t < 128) {
    float4 sv = make_float4(0.f, 0.f, 0.f, 0.f);
#pragma unroll
    for (int ww = 0; ww < 4; ++ww) {
      float4 v = *(const float4*)&red[ww * 512 + t * 4];
      sv.x += v.x; sv.y += v.y; sv.z += v.z; sv.w += v.w;
    }
    *(float4*)&out[(size_t)g * 512 + t * 4] = sv;
  }
}

extern "C" void kernel_launch(void* const* d_in, const int* in_sizes, int n_in,
                              void* d_out, int out_size, void* d_ws, size_t ws_size,
                              hipStream_t stream) {
  const float* x  = (const float*)d_in[0];
  const int* ei   = (const int*)d_in[1];
  const int* batch= (const int*)d_in[2];
  const float* eW = (const float*)d_in[3];
  const float* eb = (const float*)d_in[4];
  const float* gW = (const float*)d_in[5];
  const float* gb = (const float*)d_in[6];
  float* out = (float*)d_out;

  const int N = in_sizes[0] / 11;
  const int E = in_sizes[1] / 2;
  const int G = out_size / 512;
  const int L = in_sizes[5] / (512 * 512);

  const int* src = ei;
  const int* dst = ei + E;

  char* p = (char*)d_ws;
  auto carve = [&](size_t bytes) {
    char* q = p;
    p += (bytes + 255) & ~(size_t)255;
    return q;
  };
  ushort_t* h         = (ushort_t*)carve((size_t)N * 512 * 2);
  ushort_t* s         = (ushort_t*)carve((size_t)N * 512 * 2);
  ushort_t* Wt        = (ushort_t*)carve((size_t)L * 512 * 512 * 2);
  int* deg            = (int*)carve((size_t)N * 4);
  float* dinv         = (float*)carve((size_t)N * 4);
  float* selfn        = (float*)carve((size_t)N * 4);
  int* off            = (int*)carve(((size_t)N + 1) * 4);
  int* cur            = (int*)carve((size_t)N * 4);
  int* ssrc           = (int*)carve((size_t)E * 4);
  int* bsum           = (int*)carve(1024);
  int* bpre           = (int*)carve(1024);

  k_zero<<<(N + 255) / 256, 256, 0, stream>>>(deg, N);
  k_zero<<<(N + 255) / 256, 256, 0, stream>>>(cur, N);

  int totW = L * 512 * 512;
  k_prep_w<<<(totW + 255) / 256, 256, 0, stream>>>(gW, Wt, totW);
  k_expand<<<2048, 256, 0, stream>>>(x, eW, eb, h, N);
  k_deg<<<(E + 255) / 256, 256, 0, stream>>>(dst, deg, E);
  k_dinv<<<(N + 255) / 256, 256, 0, stream>>>(deg, dinv, selfn, N);
  int nb = (N + 1023) / 1024;
  k_scan_a<<<nb, 256, 0, stream>>>(deg, off, bsum, N);
  k_scan_b<<<1, 256, 0, stream>>>(bsum, bpre, nb, off, N, E);
  k_scan_c<<<(N + 255) / 256, 256, 0, stream>>>(off, bpre, N);
  k_fill<<<(E + 255) / 256, 256, 0, stream>>>(src, dst, off, cur, ssrc, E);

  dim3 ggrid(4, (N + 127) / 128);
  const int nwg = 4 * ((N + 127) / 128);
  const int q = nwg >> 3, r = nwg & 7;

  for (int l = 0; l < L; ++l) {
    k_agg2<<<2048, 256, 0, stream>>>(h, s, off, ssrc, dinv, selfn, N, q, r);
    k_gemm<<<ggrid, 256, 0, stream>>>(s, Wt + (size_t)l * 512 * 512,
                                      gb + (size_t)l * 512, h, N);
  }
  k_pool<<<G, 256, 0, stream>>>(h, batch, out, N);
}

// Round 16
// 1077.521 us; speedup vs baseline: 1.1802x; 1.1802x over previous
//
#include <hip/hip_runtime.h>
#include <hip/hip_bf16.h>
#include <stdint.h>

typedef __attribute__((ext_vector_type(8))) short bf16x8;
typedef __attribute__((ext_vector_type(4))) float f32x4;
typedef unsigned short ushort_t;
typedef unsigned int uint_t;

__device__ __forceinline__ unsigned short f2bf(float f) {
  unsigned u = __float_as_uint(f);
  u += 0x7fffu + ((u >> 16) & 1u);
  return (unsigned short)(u >> 16);
}
__device__ __forceinline__ float bf2f(unsigned u16) {
  return __uint_as_float(u16 << 16);
}
__device__ __forceinline__ void fma8(float* a, uint4 u, float w) {
  a[0] += w * bf2f(u.x & 0xffffu); a[1] += w * bf2f(u.x >> 16);
  a[2] += w * bf2f(u.y & 0xffffu); a[3] += w * bf2f(u.y >> 16);
  a[4] += w * bf2f(u.z & 0xffffu); a[5] += w * bf2f(u.z >> 16);
  a[6] += w * bf2f(u.w & 0xffffu); a[7] += w * bf2f(u.w >> 16);
}
__device__ __forceinline__ uint4 pack8u(const float* a) {
  uint4 p;
  p.x = (uint_t)f2bf(a[0]) | ((uint_t)f2bf(a[1]) << 16);
  p.y = (uint_t)f2bf(a[2]) | ((uint_t)f2bf(a[3]) << 16);
  p.z = (uint_t)f2bf(a[4]) | ((uint_t)f2bf(a[5]) << 16);
  p.w = (uint_t)f2bf(a[6]) | ((uint_t)f2bf(a[7]) << 16);
  return p;
}

__global__ void k_zero(int* __restrict__ p, int n) {
  int i = blockIdx.x * blockDim.x + threadIdx.x;
  if (i < n) p[i] = 0;
}

// ---- weights -> bf16, swizzled [l][nt(4)][kt(16)][kg(4)][col(128)][j(8)]
// maps to W[l][k = kt*32+kg*8+j][n = nt*128+col]
__global__ void k_prep_w(const float* __restrict__ W, ushort_t* __restrict__ Wt, int total) {
  int idx = blockIdx.x * blockDim.x + threadIdx.x;
  if (idx >= total) return;
  int j   = idx & 7;
  int col = (idx >> 3) & 127;
  int kg  = (idx >> 10) & 3;
  int kt  = (idx >> 12) & 15;
  int nt  = (idx >> 16) & 3;
  int l   = idx >> 18;
  int k = kt * 32 + kg * 8 + j;
  int n = nt * 128 + col;
  Wt[idx] = f2bf(W[((size_t)(l * 512 + k)) * 512 + n]);
}

// ---- h = log1p(x) @ expW + expb   (wave per node, grid-stride, 16B stores)
__global__ __launch_bounds__(256) void k_expand(const float* __restrict__ x,
                                                const float* __restrict__ eW,
                                                const float* __restrict__ eb,
                                                ushort_t* __restrict__ h, int N) {
  const int wid = (blockIdx.x * 256 + threadIdx.x) >> 6;
  const int nw = (gridDim.x * 256) >> 6;
  const int l = threadIdx.x & 63;

  float wf[11][8];
  float bias[8];
#pragma unroll
  for (int f = 0; f < 11; ++f) {
    float4 a = *(const float4*)&eW[f * 512 + l * 8];
    float4 b = *(const float4*)&eW[f * 512 + l * 8 + 4];
    wf[f][0] = a.x; wf[f][1] = a.y; wf[f][2] = a.z; wf[f][3] = a.w;
    wf[f][4] = b.x; wf[f][5] = b.y; wf[f][6] = b.z; wf[f][7] = b.w;
  }
  {
    float4 a = *(const float4*)&eb[l * 8];
    float4 b = *(const float4*)&eb[l * 8 + 4];
    bias[0] = a.x; bias[1] = a.y; bias[2] = a.z; bias[3] = a.w;
    bias[4] = b.x; bias[5] = b.y; bias[6] = b.z; bias[7] = b.w;
  }

  for (int n = wid; n < N; n += nw) {
    float xv = (l < 11) ? x[(size_t)n * 11 + l] : 0.f;
    float lx = log1pf(xv);
    float acc[8];
#pragma unroll
    for (int j = 0; j < 8; ++j) acc[j] = bias[j];
#pragma unroll
    for (int f = 0; f < 11; ++f) {
      float c = __shfl(lx, f, 64);
#pragma unroll
      for (int j = 0; j < 8; ++j) acc[j] += c * wf[f][j];
    }
    *(uint4*)(h + (size_t)n * 512 + l * 8) = pack8u(acc);
  }
}

__global__ void k_deg(const int* __restrict__ dst, int* __restrict__ deg, int E) {
  int e = blockIdx.x * blockDim.x + threadIdx.x;
  if (e < E) atomicAdd(&deg[dst[e]], 1);
}

__global__ void k_dinv(const int* __restrict__ deg, float* __restrict__ dinv,
                       float* __restrict__ selfn, int N) {
  int n = blockIdx.x * blockDim.x + threadIdx.x;
  if (n >= N) return;
  float d = (float)deg[n] + 2.0f;
  dinv[n] = rsqrtf(d);
  selfn[n] = 2.0f / d;
}

// ---- 2-level exclusive scan of deg -> off (CSR offsets)
__global__ void k_scan_a(const int* __restrict__ deg, int* __restrict__ off,
                         int* __restrict__ bsum, int N) {
  __shared__ int sd[256];
  int t = threadIdx.x;
  int i0 = blockIdx.x * 1024 + t * 4;
  int d[4];
#pragma unroll
  for (int j = 0; j < 4; ++j) d[j] = (i0 + j < N) ? deg[i0 + j] : 0;
  int ts = d[0] + d[1] + d[2] + d[3];
  sd[t] = ts;
  __syncthreads();
  for (int o = 1; o < 256; o <<= 1) {
    int v = (t >= o) ? sd[t - o] : 0;
    __syncthreads();
    sd[t] += v;
    __syncthreads();
  }
  int incl = sd[t];
  int run = incl - ts;
#pragma unroll
  for (int j = 0; j < 4; ++j) {
    if (i0 + j < N) off[i0 + j] = run;
    run += d[j];
  }
  if (t == 255) bsum[blockIdx.x] = incl;
}

__global__ void k_scan_b(const int* __restrict__ bsum, int* __restrict__ bpre, int nb,
                         int* __restrict__ off, int N, int E) {
  __shared__ int sd[256];
  int t = threadIdx.x;
  int v = (t < nb) ? bsum[t] : 0;
  sd[t] = v;
  __syncthreads();
  for (int o = 1; o < 256; o <<= 1) {
    int u = (t >= o) ? sd[t - o] : 0;
    __syncthreads();
    sd[t] += u;
    __syncthreads();
  }
  if (t < nb) bpre[t] = sd[t] - v;
  if (t == 0) off[N] = E;
}

__global__ void k_scan_c(int* __restrict__ off, const int* __restrict__ bpre, int N) {
  int i = blockIdx.x * blockDim.x + threadIdx.x;
  if (i < N) off[i] += bpre[i >> 10];
}

__global__ void k_fill(const int* __restrict__ src, const int* __restrict__ dst,
                       const int* __restrict__ off, int* __restrict__ cur,
                       int* __restrict__ ssrc, int E) {
  int e = blockIdx.x * blockDim.x + threadIdx.x;
  if (e >= E) return;
  int t = dst[e];
  int p = atomicAdd(&cur[t], 1);
  ssrc[off[t] + p] = src[e];
}

// ---- s = A_hat * h  (two nodes per wave, distance-1 pipelined chains;
//      node ranges aligned to the GEMM's XCD-chunk map)
__global__ __launch_bounds__(256) void k_agg2(const ushort_t* __restrict__ h,
                                              ushort_t* __restrict__ s,
                                              const int* __restrict__ off,
                                              const int* __restrict__ ssrc,
                                              const float* __restrict__ dinv,
                                              const float* __restrict__ selfn,
                                              int N, int q, int r) {
  const int b = blockIdx.x;
  const int x = b & 7;
  const int ib = b >> 3;
  const int bpx = gridDim.x >> 3;
  const int wv = threadIdx.x >> 6;
  const int l = threadIdx.x & 63;

  auto swz_lo = [&](int xx) { return xx < r ? xx * (q + 1) : r * (q + 1) + (xx - r) * q; };
  const int node_lo = swz_lo(x) * 32;
  const int node_hi = min(N, swz_lo(x + 1) * 32);
  const int stride = bpx * 4 * 2;

  for (int n0 = node_lo + (ib * 4 + wv) * 2; n0 < node_hi; n0 += stride) {
    const int n1 = n0 + 1;
    const bool v1 = n1 < node_hi;
    int i0 = off[n0], e0 = off[n0 + 1];
    int i1 = v1 ? e0 : 0, e1 = v1 ? off[n1 + 1] : 0;
    float dn0 = dinv[n0], dn1 = v1 ? dinv[n1] : 0.f;
    float a0[8], a1[8];
    {
      uint4 u = *(const uint4*)(h + (size_t)n0 * 512 + l * 8);
      float sn = selfn[n0];
      a0[0] = sn * bf2f(u.x & 0xffffu); a0[1] = sn * bf2f(u.x >> 16);
      a0[2] = sn * bf2f(u.y & 0xffffu); a0[3] = sn * bf2f(u.y >> 16);
      a0[4] = sn * bf2f(u.z & 0xffffu); a0[5] = sn * bf2f(u.z >> 16);
      a0[6] = sn * bf2f(u.w & 0xffffu); a0[7] = sn * bf2f(u.w >> 16);
    }
#pragma unroll
    for (int j = 0; j < 8; ++j) a1[j] = 0.f;
    if (v1) {
      uint4 u = *(const uint4*)(h + (size_t)n1 * 512 + l * 8);
      fma8(a1, u, selfn[n1]);
    }

    const int cj = min(e0 - i0, e1 - i1);
    if (cj > 0) {
      int m0 = ssrc[i0], m1 = ssrc[i1];
      float w0 = dn0 * dinv[m0], w1 = dn1 * dinv[m1];
      uint4 u0 = *(const uint4*)(h + (size_t)m0 * 512 + l * 8);
      uint4 u1 = *(const uint4*)(h + (size_t)m1 * 512 + l * 8);
      for (int k = 1; k < cj; ++k) {
        int m0n = ssrc[i0 + k], m1n = ssrc[i1 + k];
        float w0n = dn0 * dinv[m0n], w1n = dn1 * dinv[m1n];
        uint4 u0n = *(const uint4*)(h + (size_t)m0n * 512 + l * 8);
        uint4 u1n = *(const uint4*)(h + (size_t)m1n * 512 + l * 8);
        fma8(a0, u0, w0);
        fma8(a1, u1, w1);
        u0 = u0n; u1 = u1n; w0 = w0n; w1 = w1n;
      }
      fma8(a0, u0, w0);
      fma8(a1, u1, w1);
      i0 += cj; i1 += cj;
    }
    if (i0 < e0) {
      int m = ssrc[i0];
      float w = dn0 * dinv[m];
      uint4 u = *(const uint4*)(h + (size_t)m * 512 + l * 8);
      for (++i0; i0 < e0; ++i0) {
        int mn = ssrc[i0];
        float wn = dn0 * dinv[mn];
        uint4 un = *(const uint4*)(h + (size_t)mn * 512 + l * 8);
        fma8(a0, u, w);
        u = un; w = wn;
      }
      fma8(a0, u, w);
    }
    if (i1 < e1) {
      int m = ssrc[i1];
      float w = dn1 * dinv[m];
      uint4 u = *(const uint4*)(h + (size_t)m * 512 + l * 8);
      for (++i1; i1 < e1; ++i1) {
        int mn = ssrc[i1];
        float wn = dn1 * dinv[mn];
        uint4 un = *(const uint4*)(h + (size_t)mn * 512 + l * 8);
        fma8(a1, u, w);
        u = un; w = wn;
      }
      fma8(a1, u, w);
    }

    *(uint4*)(s + (size_t)n0 * 512 + l * 8) = pack8u(a0);
    if (v1) *(uint4*)(s + (size_t)n1 * 512 + l * 8) = pack8u(a1);
  }
}

// ---- h += relu(s @ W[l] + b)  128x128 tile, 256 thr, 2-buffer counted-vmcnt
//      pipeline, XCD-chunked swizzle, setprio MFMA, coalesced LDS epilogue
__global__ __launch_bounds__(256) void k_gemm(const ushort_t* __restrict__ s,
                                              const ushort_t* __restrict__ Wt,
                                              const float* __restrict__ gbl,
                                              ushort_t* __restrict__ h, int N) {
  __shared__ alignas(16) ushort_t AB[2][8192];  // per buf: A [kg4][128][8] | B [kg4][128][8]
  const int tid = threadIdx.x;

  // bijective XCD-chunk swizzle (m204): same-panel nt-blocks -> same XCD, adjacent
  const int nwg = gridDim.x * gridDim.y;
  const int orig = blockIdx.y * gridDim.x + blockIdx.x;
  const int q = nwg >> 3, r = nwg & 7;
  const int xcd = orig & 7, pos = orig >> 3;
  const int swz = (xcd < r ? xcd * (q + 1) : r * (q + 1) + (xcd - r) * q) + pos;
  const int nt = swz & 3;
  const int m0 = (swz >> 2) * 128;

  const int wv = tid >> 6, ln = tid & 63;
  const int wrow = wv >> 1, wcol = wv & 1;
  const int l15 = ln & 15, l4 = ln >> 4;

  f32x4 acc[4][4];
#pragma unroll
  for (int i = 0; i < 4; ++i)
#pragma unroll
    for (int j = 0; j < 4; ++j) acc[i][j] = (f32x4){0.f, 0.f, 0.f, 0.f};

  // A staging source: lane tid covers (kg=tid>>7, row=tid&127) and (kg+2, row)
  const int arow = tid & 127, akg = tid >> 7;
  const ushort_t* pa = s + (size_t)min(m0 + arow, N - 1) * 512 + akg * 8;
  const ushort_t* wtb = Wt + ((size_t)nt << 16);

  auto stage = [&](int kt, int buf) {
    ushort_t* base = &AB[buf][0];
    const ushort_t* a0 = pa + kt * 32;
    __builtin_amdgcn_global_load_lds(
        (const __attribute__((address_space(1))) uint_t*)a0,
        (__attribute__((address_space(3))) uint_t*)&base[tid * 8], 16, 0, 0);
    __builtin_amdgcn_global_load_lds(
        (const __attribute__((address_space(1))) uint_t*)(a0 + 16),
        (__attribute__((address_space(3))) uint_t*)&base[(256 + tid) * 8], 16, 0, 0);
    const ushort_t* wt = wtb + (kt << 12);
    __builtin_amdgcn_global_load_lds(
        (const __attribute__((address_space(1))) uint_t*)(wt + tid * 8),
        (__attribute__((address_space(3))) uint_t*)&base[4096 + tid * 8], 16, 0, 0);
    __builtin_amdgcn_global_load_lds(
        (const __attribute__((address_space(1))) uint_t*)(wt + (256 + tid) * 8),
        (__attribute__((address_space(3))) uint_t*)&base[4096 + (256 + tid) * 8], 16, 0, 0);
  };

  // prologue: 2 stages in flight; wait only the first (4 loads remain in flight)
  stage(0, 0);
  stage(1, 1);
  asm volatile("s_waitcnt vmcnt(4)" ::: "memory");
  __builtin_amdgcn_s_barrier();

  for (int kt = 0; kt < 16; ++kt) {
    const int cur = kt & 1;
    bf16x8 a[4], b[4];
#pragma unroll
    for (int i = 0; i < 4; ++i)
      a[i] = *(const bf16x8*)&AB[cur][(l4 * 128 + wrow * 64 + i * 16 + l15) * 8];
#pragma unroll
    for (int j = 0; j < 4; ++j)
      b[j] = *(const bf16x8*)&AB[cur][4096 + (l4 * 128 + wcol * 64 + j * 16 + l15) * 8];
    if (kt < 14) {
      // all waves finished reading buf[cur] -> safe to overwrite with kt+2
      asm volatile("s_waitcnt lgkmcnt(0)" ::: "memory");
      __builtin_amdgcn_s_barrier();
      stage(kt + 2, cur);
    }
    __builtin_amdgcn_s_setprio(1);
#pragma unroll
    for (int i = 0; i < 4; ++i)
#pragma unroll
      for (int j = 0; j < 4; ++j)
        acc[i][j] = __builtin_amdgcn_mfma_f32_16x16x32_bf16(a[i], b[j], acc[i][j], 0, 0, 0);
    __builtin_amdgcn_s_setprio(0);
    if (kt < 14) {
      asm volatile("s_waitcnt vmcnt(4)" ::: "memory");   // stage(kt+1) arrived
      __builtin_amdgcn_s_barrier();
    } else if (kt == 14) {
      asm volatile("s_waitcnt vmcnt(0)" ::: "memory");   // last stage arrived
      __builtin_amdgcn_s_barrier();
    }
  }
  __syncthreads();  // full drain before LDS reuse

  // epilogue: 4 passes of 32 rows x 128 cols f32 through AB[0], coalesced RMW
  float* cst = (float*)&AB[0][0];  // 16KB = 32*128 f32
#pragma unroll
  for (int p = 0; p < 4; ++p) {
    const int wrow_sel = p >> 1, ipair = (p & 1) * 2;
    if (wrow == wrow_sel) {
#pragma unroll
      for (int ii = 0; ii < 2; ++ii) {
        int i = ipair + ii;
#pragma unroll
        for (int v = 0; v < 4; ++v) {
          int r32 = ii * 16 + l4 * 4 + v;
#pragma unroll
          for (int j = 0; j < 4; ++j)
            cst[r32 * 128 + wcol * 64 + j * 16 + l15] = acc[i][j][v];
        }
      }
    }
    __syncthreads();
#pragma unroll
    for (int k = 0; k < 2; ++k) {
      int u = k * 256 + tid;
      int row_l = u >> 4, cb = u & 15;
      int grow = m0 + wrow_sel * 64 + ipair * 16 + row_l;
      if (grow < N) {
        float4 c0 = *(const float4*)&cst[row_l * 128 + cb * 8];
        float4 c1 = *(const float4*)&cst[row_l * 128 + cb * 8 + 4];
        float c[8] = {c0.x, c0.y, c0.z, c0.w, c1.x, c1.y, c1.z, c1.w};
        const float* gp = gbl + nt * 128 + cb * 8;
        float4 b0 = *(const float4*)gp;
        float4 b1 = *(const float4*)(gp + 4);
        float bb[8] = {b0.x, b0.y, b0.z, b0.w, b1.x, b1.y, b1.z, b1.w};
        ushort_t* hp = h + (size_t)grow * 512 + nt * 128 + cb * 8;
        uint4 hu = *(const uint4*)hp;
        float hv[8];
        hv[0] = bf2f(hu.x & 0xffffu); hv[1] = bf2f(hu.x >> 16);
        hv[2] = bf2f(hu.y & 0xffffu); hv[3] = bf2f(hu.y >> 16);
        hv[4] = bf2f(hu.z & 0xffffu); hv[5] = bf2f(hu.z >> 16);
        hv[6] = bf2f(hu.w & 0xffffu); hv[7] = bf2f(hu.w >> 16);
#pragma unroll
        for (int j = 0; j < 8; ++j) hv[j] += fmaxf(c[j] + bb[j], 0.f);
        *(uint4*)hp = pack8u(hv);
      }
    }
    __syncthreads();
  }
}

__device__ __forceinline__ int lbound(const int* a, int n, int v) {
  int lo = 0, hi = n;
  while (lo < hi) {
    int m = (lo + hi) >> 1;
    if (a[m] < v) lo = m + 1; else hi = m;
  }
  return lo;
}

// ---- global_add_pool: block per graph, 16B loads, 4-way row parallel + LDS reduce
__global__ __launch_bounds__(256) void k_pool(const ushort_t* __restrict__ h,
                                              const int* __restrict__ batch,
                                              float* __restrict__ out, int N) {
  __shared__ float red[4 * 512];
  int g = blockIdx.x;
  int t = threadIdx.x;
  int w = t >> 6, l = t & 63;
  int start = lbound(batch, N, g);
  int end = lbound(batch, N, g + 1);
  float acc[8];
#pragma unroll
  for (int j = 0; j < 8; ++j) acc[j] = 0.f;
  for (int n = start + w; n < end; n += 4) {
    uint4 u = *(const uint4*)(h + (size_t)n * 512 + l * 8);
    acc[0] += bf2f(u.x & 0xffffu); acc[1] += bf2f(u.x >> 16);
    acc[2] += bf2f(u.y & 0xffffu); acc[3] += bf2f(u.y >> 16);
    acc[4] += bf2f(u.z & 0xffffu); acc[5] += bf2f(u.z >> 16);
    acc[6] += bf2f(u.w & 0xffffu); acc[7] += bf2f(u.w >> 16);
  }
#pragma unroll
  for (int j = 0; j < 8; ++j) red[w * 512 + l * 8 + j] = acc[j];
  __syncthreads();
  if (t < 128) {
    float4 sv = make_float4(0.f, 0.f, 0.f, 0.f);
#pragma unroll
    for (int ww = 0; ww < 4; ++ww) {
      float4 v = *(const float4*)&red[ww * 512 + t * 4];
      sv.x += v.x; sv.y += v.y; sv.z += v.z; sv.w += v.w;
    }
    *(float4*)&out[(size_t)g * 512 + t * 4] = sv;
  }
}

extern "C" void kernel_launch(void* const* d_in, const int* in_sizes, int n_in,
                              void* d_out, int out_size, void* d_ws, size_t ws_size,
                              hipStream_t stream) {
  const float* x  = (const float*)d_in[0];
  const int* ei   = (const int*)d_in[1];
  const int* batch= (const int*)d_in[2];
  const float* eW = (const float*)d_in[3];
  const float* eb = (const float*)d_in[4];
  const float* gW = (const float*)d_in[5];
  const float* gb = (const float*)d_in[6];
  float* out = (float*)d_out;

  const int N = in_sizes[0] / 11;
  const int E = in_sizes[1] / 2;
  const int G = out_size / 512;
  const int L = in_sizes[5] / (512 * 512);

  const int* src = ei;
  const int* dst = ei + E;

  char* p = (char*)d_ws;
  auto carve = [&](size_t bytes) {
    char* q = p;
    p += (bytes + 255) & ~(size_t)255;
    return q;
  };
  ushort_t* h         = (ushort_t*)carve((size_t)N * 512 * 2);
  ushort_t* s         = (ushort_t*)carve((size_t)N * 512 * 2);
  ushort_t* Wt        = (ushort_t*)carve((size_t)L * 512 * 512 * 2);
  int* deg            = (int*)carve((size_t)N * 4);
  float* dinv         = (float*)carve((size_t)N * 4);
  float* selfn        = (float*)carve((size_t)N * 4);
  int* off            = (int*)carve(((size_t)N + 1) * 4);
  int* cur            = (int*)carve((size_t)N * 4);
  int* ssrc           = (int*)carve((size_t)E * 4);
  int* bsum           = (int*)carve(1024);
  int* bpre           = (int*)carve(1024);

  k_zero<<<(N + 255) / 256, 256, 0, stream>>>(deg, N);
  k_zero<<<(N + 255) / 256, 256, 0, stream>>>(cur, N);

  int totW = L * 512 * 512;
  k_prep_w<<<(totW + 255) / 256, 256, 0, stream>>>(gW, Wt, totW);
  k_expand<<<2048, 256, 0, stream>>>(x, eW, eb, h, N);
  k_deg<<<(E + 255) / 256, 256, 0, stream>>>(dst, deg, E);
  k_dinv<<<(N + 255) / 256, 256, 0, stream>>>(deg, dinv, selfn, N);
  int nb = (N + 1023) / 1024;
  k_scan_a<<<nb, 256, 0, stream>>>(deg, off, bsum, N);
  k_scan_b<<<1, 256, 0, stream>>>(bsum, bpre, nb, off, N, E);
  k_scan_c<<<(N + 255) / 256, 256, 0, stream>>>(off, bpre, N);
  k_fill<<<(E + 255) / 256, 256, 0, stream>>>(src, dst, off, cur, ssrc, E);

  // gemm grid + its XCD-chunk parameters (shared with agg2's node mapping)
  dim3 ggrid(4, (N + 127) / 128);
  const int nwg = 4 * ((N + 127) / 128);
  const int q = nwg >> 3, r = nwg & 7;

  for (int l = 0; l < L; ++l) {
    k_agg2<<<2048, 256, 0, stream>>>(h, s, off, ssrc, dinv, selfn, N, q, r);
    k_gemm<<<ggrid, 256, 0, stream>>>(s, Wt + (size_t)l * 512 * 512,
                                      gb + (size_t)l * 512, h, N);
  }
  k_pool<<<G, 256, 0, stream>>>(h, batch, out, N);
}

// Round 17
// 1029.802 us; speedup vs baseline: 1.2349x; 1.0463x over previous
//
#include <hip/hip_runtime.h>
#include <hip/hip_bf16.h>
#include <stdint.h>

typedef __attribute__((ext_vector_type(8))) short bf16x8;
typedef __attribute__((ext_vector_type(4))) float f32x4;
typedef unsigned short ushort_t;
typedef unsigned int uint_t;

__device__ __forceinline__ unsigned short f2bf(float f) {
  unsigned u = __float_as_uint(f);
  u += 0x7fffu + ((u >> 16) & 1u);
  return (unsigned short)(u >> 16);
}
__device__ __forceinline__ float bf2f(unsigned u16) {
  return __uint_as_float(u16 << 16);
}
__device__ __forceinline__ void fma8(float* a, uint4 u, float w) {
  a[0] += w * bf2f(u.x & 0xffffu); a[1] += w * bf2f(u.x >> 16);
  a[2] += w * bf2f(u.y & 0xffffu); a[3] += w * bf2f(u.y >> 16);
  a[4] += w * bf2f(u.z & 0xffffu); a[5] += w * bf2f(u.z >> 16);
  a[6] += w * bf2f(u.w & 0xffffu); a[7] += w * bf2f(u.w >> 16);
}
__device__ __forceinline__ uint4 pack8u(const float* a) {
  uint4 p;
  p.x = (uint_t)f2bf(a[0]) | ((uint_t)f2bf(a[1]) << 16);
  p.y = (uint_t)f2bf(a[2]) | ((uint_t)f2bf(a[3]) << 16);
  p.z = (uint_t)f2bf(a[4]) | ((uint_t)f2bf(a[5]) << 16);
  p.w = (uint_t)f2bf(a[6]) | ((uint_t)f2bf(a[7]) << 16);
  return p;
}

__global__ void k_zero(int* __restrict__ p, int n) {
  int i = blockIdx.x * blockDim.x + threadIdx.x;
  if (i < n) p[i] = 0;
}

// ---- weights -> bf16, swizzled [l][nt(4)][kt(16)][kg(4)][col(128)][j(8)]
// maps to W[l][k = kt*32+kg*8+j][n = nt*128+col]
__global__ void k_prep_w(const float* __restrict__ W, ushort_t* __restrict__ Wt, int total) {
  int idx = blockIdx.x * blockDim.x + threadIdx.x;
  if (idx >= total) return;
  int j   = idx & 7;
  int col = (idx >> 3) & 127;
  int kg  = (idx >> 10) & 3;
  int kt  = (idx >> 12) & 15;
  int nt  = (idx >> 16) & 3;
  int l   = idx >> 18;
  int k = kt * 32 + kg * 8 + j;
  int n = nt * 128 + col;
  Wt[idx] = f2bf(W[((size_t)(l * 512 + k)) * 512 + n]);
}

// ---- h = log1p(x) @ expW + expb   (wave per node, grid-stride, 16B stores)
__global__ __launch_bounds__(256) void k_expand(const float* __restrict__ x,
                                                const float* __restrict__ eW,
                                                const float* __restrict__ eb,
                                                ushort_t* __restrict__ h, int N) {
  const int wid = (blockIdx.x * 256 + threadIdx.x) >> 6;
  const int nw = (gridDim.x * 256) >> 6;
  const int l = threadIdx.x & 63;

  float wf[11][8];
  float bias[8];
#pragma unroll
  for (int f = 0; f < 11; ++f) {
    float4 a = *(const float4*)&eW[f * 512 + l * 8];
    float4 b = *(const float4*)&eW[f * 512 + l * 8 + 4];
    wf[f][0] = a.x; wf[f][1] = a.y; wf[f][2] = a.z; wf[f][3] = a.w;
    wf[f][4] = b.x; wf[f][5] = b.y; wf[f][6] = b.z; wf[f][7] = b.w;
  }
  {
    float4 a = *(const float4*)&eb[l * 8];
    float4 b = *(const float4*)&eb[l * 8 + 4];
    bias[0] = a.x; bias[1] = a.y; bias[2] = a.z; bias[3] = a.w;
    bias[4] = b.x; bias[5] = b.y; bias[6] = b.z; bias[7] = b.w;
  }

  for (int n = wid; n < N; n += nw) {
    float xv = (l < 11) ? x[(size_t)n * 11 + l] : 0.f;
    float lx = log1pf(xv);
    float acc[8];
#pragma unroll
    for (int j = 0; j < 8; ++j) acc[j] = bias[j];
#pragma unroll
    for (int f = 0; f < 11; ++f) {
      float c = __shfl(lx, f, 64);
#pragma unroll
      for (int j = 0; j < 8; ++j) acc[j] += c * wf[f][j];
    }
    *(uint4*)(h + (size_t)n * 512 + l * 8) = pack8u(acc);
  }
}

__global__ void k_deg(const int* __restrict__ dst, int* __restrict__ deg, int E) {
  int e = blockIdx.x * blockDim.x + threadIdx.x;
  if (e < E) atomicAdd(&deg[dst[e]], 1);
}

__global__ void k_dinv(const int* __restrict__ deg, float* __restrict__ dinv,
                       float* __restrict__ selfn, int N) {
  int n = blockIdx.x * blockDim.x + threadIdx.x;
  if (n >= N) return;
  float d = (float)deg[n] + 2.0f;
  dinv[n] = rsqrtf(d);
  selfn[n] = 2.0f / d;
}

// ---- 2-level exclusive scan of deg -> off (CSR offsets)
__global__ void k_scan_a(const int* __restrict__ deg, int* __restrict__ off,
                         int* __restrict__ bsum, int N) {
  __shared__ int sd[256];
  int t = threadIdx.x;
  int i0 = blockIdx.x * 1024 + t * 4;
  int d[4];
#pragma unroll
  for (int j = 0; j < 4; ++j) d[j] = (i0 + j < N) ? deg[i0 + j] : 0;
  int ts = d[0] + d[1] + d[2] + d[3];
  sd[t] = ts;
  __syncthreads();
  for (int o = 1; o < 256; o <<= 1) {
    int v = (t >= o) ? sd[t - o] : 0;
    __syncthreads();
    sd[t] += v;
    __syncthreads();
  }
  int incl = sd[t];
  int run = incl - ts;
#pragma unroll
  for (int j = 0; j < 4; ++j) {
    if (i0 + j < N) off[i0 + j] = run;
    run += d[j];
  }
  if (t == 255) bsum[blockIdx.x] = incl;
}

__global__ void k_scan_b(const int* __restrict__ bsum, int* __restrict__ bpre, int nb,
                         int* __restrict__ off, int N, int E) {
  __shared__ int sd[256];
  int t = threadIdx.x;
  int v = (t < nb) ? bsum[t] : 0;
  sd[t] = v;
  __syncthreads();
  for (int o = 1; o < 256; o <<= 1) {
    int u = (t >= o) ? sd[t - o] : 0;
    __syncthreads();
    sd[t] += u;
    __syncthreads();
  }
  if (t < nb) bpre[t] = sd[t] - v;
  if (t == 0) off[N] = E;
}

__global__ void k_scan_c(int* __restrict__ off, const int* __restrict__ bpre, int N) {
  int i = blockIdx.x * blockDim.x + threadIdx.x;
  if (i < N) off[i] += bpre[i >> 10];
}

__global__ void k_fill(const int* __restrict__ src, const int* __restrict__ dst,
                       const int* __restrict__ off, int* __restrict__ cur,
                       int* __restrict__ ssrc, int E) {
  int e = blockIdx.x * blockDim.x + threadIdx.x;
  if (e >= E) return;
  int t = dst[e];
  int p = atomicAdd(&cur[t], 1);
  ssrc[off[t] + p] = src[e];
}

// ---- s = A_hat * h  (two nodes per wave, distance-1 pipelined chains;
//      node ranges aligned to the GEMM's XCD-chunk map)
__global__ __launch_bounds__(256) void k_agg2(const ushort_t* __restrict__ h,
                                              ushort_t* __restrict__ s,
                                              const int* __restrict__ off,
                                              const int* __restrict__ ssrc,
                                              const float* __restrict__ dinv,
                                              const float* __restrict__ selfn,
                                              int N, int q, int r) {
  const int b = blockIdx.x;
  const int x = b & 7;
  const int ib = b >> 3;
  const int bpx = gridDim.x >> 3;
  const int wv = threadIdx.x >> 6;
  const int l = threadIdx.x & 63;

  auto swz_lo = [&](int xx) { return xx < r ? xx * (q + 1) : r * (q + 1) + (xx - r) * q; };
  const int node_lo = swz_lo(x) * 32;
  const int node_hi = min(N, swz_lo(x + 1) * 32);
  const int stride = bpx * 4 * 2;

  for (int n0 = node_lo + (ib * 4 + wv) * 2; n0 < node_hi; n0 += stride) {
    const int n1 = n0 + 1;
    const bool v1 = n1 < node_hi;
    int i0 = off[n0], e0 = off[n0 + 1];
    int i1 = v1 ? e0 : 0, e1 = v1 ? off[n1 + 1] : 0;
    float dn0 = dinv[n0], dn1 = v1 ? dinv[n1] : 0.f;
    float a0[8], a1[8];
    {
      uint4 u = *(const uint4*)(h + (size_t)n0 * 512 + l * 8);
      float sn = selfn[n0];
      a0[0] = sn * bf2f(u.x & 0xffffu); a0[1] = sn * bf2f(u.x >> 16);
      a0[2] = sn * bf2f(u.y & 0xffffu); a0[3] = sn * bf2f(u.y >> 16);
      a0[4] = sn * bf2f(u.z & 0xffffu); a0[5] = sn * bf2f(u.z >> 16);
      a0[6] = sn * bf2f(u.w & 0xffffu); a0[7] = sn * bf2f(u.w >> 16);
    }
#pragma unroll
    for (int j = 0; j < 8; ++j) a1[j] = 0.f;
    if (v1) {
      uint4 u = *(const uint4*)(h + (size_t)n1 * 512 + l * 8);
      fma8(a1, u, selfn[n1]);
    }

    const int cj = min(e0 - i0, e1 - i1);
    if (cj > 0) {
      int m0 = ssrc[i0], m1 = ssrc[i1];
      float w0 = dn0 * dinv[m0], w1 = dn1 * dinv[m1];
      uint4 u0 = *(const uint4*)(h + (size_t)m0 * 512 + l * 8);
      uint4 u1 = *(const uint4*)(h + (size_t)m1 * 512 + l * 8);
      for (int k = 1; k < cj; ++k) {
        int m0n = ssrc[i0 + k], m1n = ssrc[i1 + k];
        float w0n = dn0 * dinv[m0n], w1n = dn1 * dinv[m1n];
        uint4 u0n = *(const uint4*)(h + (size_t)m0n * 512 + l * 8);
        uint4 u1n = *(const uint4*)(h + (size_t)m1n * 512 + l * 8);
        fma8(a0, u0, w0);
        fma8(a1, u1, w1);
        u0 = u0n; u1 = u1n; w0 = w0n; w1 = w1n;
      }
      fma8(a0, u0, w0);
      fma8(a1, u1, w1);
      i0 += cj; i1 += cj;
    }
    if (i0 < e0) {
      int m = ssrc[i0];
      float w = dn0 * dinv[m];
      uint4 u = *(const uint4*)(h + (size_t)m * 512 + l * 8);
      for (++i0; i0 < e0; ++i0) {
        int mn = ssrc[i0];
        float wn = dn0 * dinv[mn];
        uint4 un = *(const uint4*)(h + (size_t)mn * 512 + l * 8);
        fma8(a0, u, w);
        u = un; w = wn;
      }
      fma8(a0, u, w);
    }
    if (i1 < e1) {
      int m = ssrc[i1];
      float w = dn1 * dinv[m];
      uint4 u = *(const uint4*)(h + (size_t)m * 512 + l * 8);
      for (++i1; i1 < e1; ++i1) {
        int mn = ssrc[i1];
        float wn = dn1 * dinv[mn];
        uint4 un = *(const uint4*)(h + (size_t)mn * 512 + l * 8);
        fma8(a1, u, w);
        u = un; w = wn;
      }
      fma8(a1, u, w);
    }

    *(uint4*)(s + (size_t)n0 * 512 + l * 8) = pack8u(a0);
    if (v1) *(uint4*)(s + (size_t)n1 * 512 + l * 8) = pack8u(a1);
  }
}

// ---- h += relu(s @ W[l] + b)  128x128 tile, 512 thr (8 waves of 32x64),
//      2-buffer counted-vmcnt pipeline, one global_load_lds per operand/stage,
//      XCD-chunked swizzle, setprio MFMA, coalesced LDS epilogue
__global__ __launch_bounds__(512) void k_gemm(const ushort_t* __restrict__ s,
                                              const ushort_t* __restrict__ Wt,
                                              const float* __restrict__ gbl,
                                              ushort_t* __restrict__ h, int N) {
  __shared__ alignas(16) ushort_t AB[2][8192];  // per buf: A [kg4][128][8] | B [kg4][128][8]
  const int tid = threadIdx.x;

  // bijective XCD-chunk swizzle (m204): same-panel nt-blocks -> same XCD, adjacent
  const int nwg = gridDim.x * gridDim.y;
  const int orig = blockIdx.y * gridDim.x + blockIdx.x;
  const int q = nwg >> 3, r = nwg & 7;
  const int xcd = orig & 7, pos = orig >> 3;
  const int swz = (xcd < r ? xcd * (q + 1) : r * (q + 1) + (xcd - r) * q) + pos;
  const int nt = swz & 3;
  const int m0 = (swz >> 2) * 128;

  const int wv = tid >> 6, ln = tid & 63;
  const int wrow = wv >> 1;          // 0..3 -> 32-row band
  const int wcol = wv & 1;           // 0..1 -> 64-col band
  const int l15 = ln & 15, l4 = ln >> 4;

  f32x4 acc[2][4];
#pragma unroll
  for (int i = 0; i < 2; ++i)
#pragma unroll
    for (int j = 0; j < 4; ++j) acc[i][j] = (f32x4){0.f, 0.f, 0.f, 0.f};

  // staging source: tid = akg*128 + arow  (512 lanes cover A 8KB in ONE load)
  const int arow = tid & 127, akg = tid >> 7;
  const ushort_t* pa = s + (size_t)min(m0 + arow, N - 1) * 512 + akg * 8;
  const ushort_t* wtb = Wt + ((size_t)nt << 16);

  auto stage = [&](int kt, int buf) {
    ushort_t* base = &AB[buf][0];
    __builtin_amdgcn_global_load_lds(
        (const __attribute__((address_space(1))) uint_t*)(pa + kt * 32),
        (__attribute__((address_space(3))) uint_t*)&base[tid * 8], 16, 0, 0);
    __builtin_amdgcn_global_load_lds(
        (const __attribute__((address_space(1))) uint_t*)(wtb + (kt << 12) + tid * 8),
        (__attribute__((address_space(3))) uint_t*)&base[4096 + tid * 8], 16, 0, 0);
  };

  // prologue: 2 stages (2 loads each) in flight; wait only the first
  stage(0, 0);
  stage(1, 1);
  asm volatile("s_waitcnt vmcnt(2)" ::: "memory");
  __builtin_amdgcn_s_barrier();

  for (int kt = 0; kt < 16; ++kt) {
    const int cur = kt & 1;
    bf16x8 a[2], b[4];
#pragma unroll
    for (int i = 0; i < 2; ++i)
      a[i] = *(const bf16x8*)&AB[cur][(l4 * 128 + wrow * 32 + i * 16 + l15) * 8];
#pragma unroll
    for (int j = 0; j < 4; ++j)
      b[j] = *(const bf16x8*)&AB[cur][4096 + (l4 * 128 + wcol * 64 + j * 16 + l15) * 8];
    if (kt < 14) {
      // all waves finished reading buf[cur] -> safe to overwrite with kt+2
      asm volatile("s_waitcnt lgkmcnt(0)" ::: "memory");
      __builtin_amdgcn_s_barrier();
      stage(kt + 2, cur);
    }
    __builtin_amdgcn_s_setprio(1);
#pragma unroll
    for (int i = 0; i < 2; ++i)
#pragma unroll
      for (int j = 0; j < 4; ++j)
        acc[i][j] = __builtin_amdgcn_mfma_f32_16x16x32_bf16(a[i], b[j], acc[i][j], 0, 0, 0);
    __builtin_amdgcn_s_setprio(0);
    if (kt < 14) {
      asm volatile("s_waitcnt vmcnt(2)" ::: "memory");   // stage(kt+1) arrived
      __builtin_amdgcn_s_barrier();
    } else if (kt == 14) {
      asm volatile("s_waitcnt vmcnt(0)" ::: "memory");   // last stage arrived
      __builtin_amdgcn_s_barrier();
    }
  }
  __syncthreads();  // full drain before LDS reuse

  // epilogue: 4 passes of 32 rows x 128 cols f32 through AB[0], coalesced RMW
  float* cst = (float*)&AB[0][0];  // 16KB = 32*128 f32
#pragma unroll
  for (int p = 0; p < 4; ++p) {
    if (wrow == p) {
#pragma unroll
      for (int i = 0; i < 2; ++i)
#pragma unroll
        for (int v = 0; v < 4; ++v) {
          int r32 = i * 16 + l4 * 4 + v;
#pragma unroll
          for (int j = 0; j < 4; ++j)
            cst[r32 * 128 + wcol * 64 + j * 16 + l15] = acc[i][j][v];
        }
    }
    __syncthreads();
    {
      int row_l = tid >> 4, cb = tid & 15;   // 512 thr = 32 rows x 16 uint4
      int grow = m0 + p * 32 + row_l;
      if (grow < N) {
        float4 c0 = *(const float4*)&cst[row_l * 128 + cb * 8];
        float4 c1 = *(const float4*)&cst[row_l * 128 + cb * 8 + 4];
        float c[8] = {c0.x, c0.y, c0.z, c0.w, c1.x, c1.y, c1.z, c1.w};
        const float* gp = gbl + nt * 128 + cb * 8;
        float4 b0 = *(const float4*)gp;
        float4 b1 = *(const float4*)(gp + 4);
        float bb[8] = {b0.x, b0.y, b0.z, b0.w, b1.x, b1.y, b1.z, b1.w};
        ushort_t* hp = h + (size_t)grow * 512 + nt * 128 + cb * 8;
        uint4 hu = *(const uint4*)hp;
        float hv[8];
        hv[0] = bf2f(hu.x & 0xffffu); hv[1] = bf2f(hu.x >> 16);
        hv[2] = bf2f(hu.y & 0xffffu); hv[3] = bf2f(hu.y >> 16);
        hv[4] = bf2f(hu.z & 0xffffu); hv[5] = bf2f(hu.z >> 16);
        hv[6] = bf2f(hu.w & 0xffffu); hv[7] = bf2f(hu.w >> 16);
#pragma unroll
        for (int j = 0; j < 8; ++j) hv[j] += fmaxf(c[j] + bb[j], 0.f);
        *(uint4*)hp = pack8u(hv);
      }
    }
    __syncthreads();
  }
}

__device__ __forceinline__ int lbound(const int* a, int n, int v) {
  int lo = 0, hi = n;
  while (lo < hi) {
    int m = (lo + hi) >> 1;
    if (a[m] < v) lo = m + 1; else hi = m;
  }
  return lo;
}

// ---- global_add_pool: block per graph, 16B loads, 4-way row parallel + LDS reduce
__global__ __launch_bounds__(256) void k_pool(const ushort_t* __restrict__ h,
                                              const int* __restrict__ batch,
                                              float* __restrict__ out, int N) {
  __shared__ float red[4 * 512];
  int g = blockIdx.x;
  int t = threadIdx.x;
  int w = t >> 6, l = t & 63;
  int start = lbound(batch, N, g);
  int end = lbound(batch, N, g + 1);
  float acc[8];
#pragma unroll
  for (int j = 0; j < 8; ++j) acc[j] = 0.f;
  for (int n = start + w; n < end; n += 4) {
    uint4 u = *(const uint4*)(h + (size_t)n * 512 + l * 8);
    acc[0] += bf2f(u.x & 0xffffu); acc[1] += bf2f(u.x >> 16);
    acc[2] += bf2f(u.y & 0xffffu); acc[3] += bf2f(u.y >> 16);
    acc[4] += bf2f(u.z & 0xffffu); acc[5] += bf2f(u.z >> 16);
    acc[6] += bf2f(u.w & 0xffffu); acc[7] += bf2f(u.w >> 16);
  }
#pragma unroll
  for (int j = 0; j < 8; ++j) red[w * 512 + l * 8 + j] = acc[j];
  __syncthreads();
  if (t < 128) {
    float4 sv = make_float4(0.f, 0.f, 0.f, 0.f);
#pragma unroll
    for (int ww = 0; ww < 4; ++ww) {
      float4 v = *(const float4*)&red[ww * 512 + t * 4];
      sv.x += v.x; sv.y += v.y; sv.z += v.z; sv.w += v.w;
    }
    *(float4*)&out[(size_t)g * 512 + t * 4] = sv;
  }
}

extern "C" void kernel_launch(void* const* d_in, const int* in_sizes, int n_in,
                              void* d_out, int out_size, void* d_ws, size_t ws_size,
                              hipStream_t stream) {
  const float* x  = (const float*)d_in[0];
  const int* ei   = (const int*)d_in[1];
  const int* batch= (const int*)d_in[2];
  const float* eW = (const float*)d_in[3];
  const float* eb = (const float*)d_in[4];
  const float* gW = (const float*)d_in[5];
  const float* gb = (const float*)d_in[6];
  float* out = (float*)d_out;

  const int N = in_sizes[0] / 11;
  const int E = in_sizes[1] / 2;
  const int G = out_size / 512;
  const int L = in_sizes[5] / (512 * 512);

  const int* src = ei;
  const int* dst = ei + E;

  char* p = (char*)d_ws;
  auto carve = [&](size_t bytes) {
    char* q = p;
    p += (bytes + 255) & ~(size_t)255;
    return q;
  };
  ushort_t* h         = (ushort_t*)carve((size_t)N * 512 * 2);
  ushort_t* s         = (ushort_t*)carve((size_t)N * 512 * 2);
  ushort_t* Wt        = (ushort_t*)carve((size_t)L * 512 * 512 * 2);
  int* deg            = (int*)carve((size_t)N * 4);
  float* dinv         = (float*)carve((size_t)N * 4);
  float* selfn        = (float*)carve((size_t)N * 4);
  int* off            = (int*)carve(((size_t)N + 1) * 4);
  int* cur            = (int*)carve((size_t)N * 4);
  int* ssrc           = (int*)carve((size_t)E * 4);
  int* bsum           = (int*)carve(1024);
  int* bpre           = (int*)carve(1024);

  k_zero<<<(N + 255) / 256, 256, 0, stream>>>(deg, N);
  k_zero<<<(N + 255) / 256, 256, 0, stream>>>(cur, N);

  int totW = L * 512 * 512;
  k_prep_w<<<(totW + 255) / 256, 256, 0, stream>>>(gW, Wt, totW);
  k_expand<<<2048, 256, 0, stream>>>(x, eW, eb, h, N);
  k_deg<<<(E + 255) / 256, 256, 0, stream>>>(dst, deg, E);
  k_dinv<<<(N + 255) / 256, 256, 0, stream>>>(deg, dinv, selfn, N);
  int nb = (N + 1023) / 1024;
  k_scan_a<<<nb, 256, 0, stream>>>(deg, off, bsum, N);
  k_scan_b<<<1, 256, 0, stream>>>(bsum, bpre, nb, off, N, E);
  k_scan_c<<<(N + 255) / 256, 256, 0, stream>>>(off, bpre, N);
  k_fill<<<(E + 255) / 256, 256, 0, stream>>>(src, dst, off, cur, ssrc, E);

  // gemm grid + its XCD-chunk parameters (shared with agg2's node mapping)
  dim3 ggrid(4, (N + 127) / 128);
  const int nwg = 4 * ((N + 127) / 128);
  const int q = nwg >> 3, r = nwg & 7;

  for (int l = 0; l < L; ++l) {
    k_agg2<<<2048, 256, 0, stream>>>(h, s, off, ssrc, dinv, selfn, N, q, r);
    k_gemm<<<ggrid, 512, 0, stream>>>(s, Wt + (size_t)l * 512 * 512,
                                      gb + (size_t)l * 512, h, N);
  }
  k_pool<<<G, 256, 0, stream>>>(h, batch, out, N);
}